// Round 5
// baseline (3586.028 us; speedup 1.0000x reference)
//
#include <hip/hip_runtime.h>

// 4-layer bidirectional LSTM, B=128, T=4096, H=13 (gates 4H=52).
// One wave per (batch, direction). Quad layout: lane l -> unit j=l>>2, gate q=l&3
// (q: 0=i,1=f,2=g,3=o). Cross-lane via readlane (const lanes) + DPP quad
// broadcasts. Two-step software pipeline: row s+1's ds_reads issue before step
// s's serial chain so LDS latency hides under the recurrence.

constexpr int T_LEN = 4096;
constexpr int BATCH = 128;
constexpr int CH    = 64;                      // timesteps per LDS chunk
constexpr float LOG2E = 1.4426950408889634f;

__device__ __forceinline__ float rl_f(float v, int lane) {
    return __int_as_float(__builtin_amdgcn_readlane(__float_as_int(v), lane));
}
template<int PAT>
__device__ __forceinline__ float qb(float v) {
    // quad_perm broadcast: 0x00->lane0, 0x55->lane1, 0xAA->lane2, 0xFF->lane3
    return __int_as_float(__builtin_amdgcn_update_dpp(0, __float_as_int(v), PAT, 0xf, 0xf, true));
}

template<int K>
__global__ __launch_bounds__(64, 1)
void lstm_seq(const float* __restrict__ act,   // [B][T][K]
              const float* __restrict__ wih,   // [2][52][K]
              const float* __restrict__ whh,   // [2][52][13]
              const float* __restrict__ bih,   // [2][52]
              const float* __restrict__ bhh,   // [2][52]
              float* __restrict__ out)         // [B][T][26]
{
    constexpr int RSF = (K == 13) ? 16 : 28;   // padded LDS row floats
    constexpr int NV  = RSF / 4;               // float4 per row (4 or 7)
    constexpr int NCH = T_LEN / CH;

    const int lane = threadIdx.x;
    const int d    = blockIdx.x & 1;
    const int b    = blockIdx.x >> 1;
    const int q    = lane & 3;                 // gate: 0=i,1=f,2=g,3=o
    const int jj   = lane >> 2;
    const int j    = (jj < 13) ? jj : 12;
    const int r    = q * 13 + j;

    // pre-scales: acc feeds exp2 directly; i-gate activation carries -2log2e so
    // the scaled cell state cst_s = -2log2e*c feeds exp2 with no serial mul.
    const float sq    = (q == 2) ? (-2.0f * LOG2E) : (-LOG2E);
    const float postA = (q == 0) ? (-2.0f * LOG2E) : ((q == 2) ? 2.0f : 1.0f);
    const float postB = (q == 2) ? -1.0f : 0.0f;

    __shared__ __align__(16) float xl[2][CH][RSF];

    float wi[K], wh[13];
    {
        const float* p = wih + (size_t)(d * 52 + r) * K;
        #pragma unroll
        for (int k = 0; k < K; ++k) wi[k] = p[k] * sq;
    }
    {
        const float* p = whh + (size_t)(d * 52 + r) * 13;
        #pragma unroll
        for (int k = 0; k < 13; ++k) wh[k] = p[k] * sq;
    }
    const float p0 = (bih[d * 52 + r] + bhh[d * 52 + r]) * sq;

    const float* actb = act + (size_t)b * T_LEN * K;

    float stag[K];
    auto load_chunk = [&](int c) {
        const int gbase = d ? (T_LEN - CH * (c + 1)) : (CH * c);
        const float* p  = actb + (size_t)(gbase + lane) * K;
        if constexpr (K == 26) {
            const float2* p2 = reinterpret_cast<const float2*>(p);
            #pragma unroll
            for (int i = 0; i < 13; ++i) { float2 v = p2[i]; stag[2*i] = v.x; stag[2*i+1] = v.y; }
        } else {
            #pragma unroll
            for (int i = 0; i < K; ++i) stag[i] = p[i];
        }
    };
    auto write_chunk = [&](int nb) {
        const int lrow = d ? (CH - 1 - lane) : lane;
        float* rowp = &xl[nb][lrow][0];
        #pragma unroll
        for (int i = 0; i + 4 <= K; i += 4)
            *reinterpret_cast<float4*>(rowp + i) = make_float4(stag[i], stag[i+1], stag[i+2], stag[i+3]);
        if constexpr (K == 26)
            *reinterpret_cast<float2*>(rowp + 24) = make_float2(stag[24], stag[25]);
        else
            rowp[12] = stag[12];
    };

    // ds_read a whole padded row into a register buffer (issue; latency hidden
    // under the subsequent step chain). Pads load garbage but are never FMA'd.
    auto ld_row = [&](const float* rowp, float4 (&v)[NV]) {
        const float4* r4 = reinterpret_cast<const float4*>(rowp);
        #pragma unroll
        for (int i = 0; i < NV; ++i) v[i] = r4[i];
    };

    float a0, a1, a2, a3;                       // pipelined input-dot partials
    auto xdot_v = [&](const float4 (&v)[NV]) {
        float c0 = p0, c1 = 0.f, c2 = 0.f, c3 = 0.f;
        constexpr int NF = K / 4;               // full float4s of data (3 or 6)
        #pragma unroll
        for (int i = 0; i < NF; ++i) {
            c0 = fmaf(v[i].x, wi[4*i],     c0);
            c1 = fmaf(v[i].y, wi[4*i + 1], c1);
            c2 = fmaf(v[i].z, wi[4*i + 2], c2);
            c3 = fmaf(v[i].w, wi[4*i + 3], c3);
        }
        if constexpr (K == 26) {
            c0 = fmaf(v[6].x, wi[24], c0);
            c1 = fmaf(v[6].y, wi[25], c1);
        } else {
            c0 = fmaf(v[3].x, wi[12], c0);
        }
        a0 = c0; a1 = c1; a2 = c2; a3 = c3;
    };

    float hreg = 0.0f, cst = 0.0f;              // cst holds -2log2e * c
    float* outp = out + ((size_t)b * T_LEN + (d ? T_LEN - 1 : 0)) * 26 + d * 13 + j;
    const int ostep    = d ? -26 : 26;
    const bool dostore = (q == 0) && (jj < 13);

    auto step = [&]() {
        float bb[4] = {a0, a1, a2, a3};
        #pragma unroll
        for (int k = 0; k < 13; ++k) {
            float hk = rl_f(hreg, 4 * k);       // const-lane readlane -> SGPR
            bb[k & 3] = fmaf(hk, wh[k], bb[k & 3]);
        }
        float acc = (bb[0] + bb[1]) + (bb[2] + bb[3]);
        float u   = __builtin_amdgcn_exp2f(acc);
        float sg  = __builtin_amdgcn_rcpf(1.0f + u);
        float a   = fmaf(postA, sg, postB);     // sigmoid / tanh / -2log2e*sigmoid(i)
        float iv = qb<0x00>(a);
        float fv = qb<0x55>(a);
        float gv = qb<0xAA>(a);
        float ov = qb<0xFF>(a);
        float ivg = iv * gv;                    // carries -2log2e
        cst = fmaf(fv, cst, ivg);               // scaled cell state
        float u2  = __builtin_amdgcn_exp2f(cst);
        float r2  = __builtin_amdgcn_rcpf(1.0f + u2);
        float ov2 = ov + ov;                    // off critical path
        hreg = fmaf(ov2, r2, -ov);              // ov*(2*r2-1)
        if (dostore) *outp = hreg;
        outp += ostep;
    };

    // prologue: stage chunk 0, start global loads for chunk 1, prime pipeline
    load_chunk(0);
    write_chunk(0);
    load_chunk(1);

    float4 vA[NV], vB[NV];
    ld_row(&xl[0][0][0], vA);
    xdot_v(vA);                                  // partials for step 0

    for (int c = 0; c < NCH; ++c) {
        const float* xb = &xl[c & 1][0][0];
        #pragma unroll 4
        for (int s = 0; s < CH; s += 2) {
            // issue row s+1 reads BEFORE step s's chain (latency hidden)
            ld_row(xb + (s + 1) * RSF, vB);
            step();                              // step s (uses a0..a3)
            xdot_v(vB);                          // partials for step s+1
            const int s2 = (s + 2 < CH) ? (s + 2) : (CH - 1);  // clamp: dummy at tail
            ld_row(xb + s2 * RSF, vA);
            step();                              // step s+1
            xdot_v(vA);                          // partials for step s+2 (dummy at tail)
        }
        if (c + 1 < NCH) {
            write_chunk((c + 1) & 1);            // staged regs -> other LDS buffer
            if (c + 2 < NCH) load_chunk(c + 2);  // issue next global loads
            ld_row(&xl[(c + 1) & 1][0][0], vA);  // after ds_writes (compiler waits)
            xdot_v(vA);                          // re-prime for new chunk's step 0
        }
    }
}

extern "C" void kernel_launch(void* const* d_in, const int* in_sizes, int n_in,
                              void* d_out, int out_size, void* d_ws, size_t ws_size,
                              hipStream_t stream) {
    const float* x     = (const float*)d_in[0];
    const float* w_ih0 = (const float*)d_in[1];
    const float* w_hh0 = (const float*)d_in[2];
    const float* b_ih0 = (const float*)d_in[3];
    const float* b_hh0 = (const float*)d_in[4];
    const float* w_ihr = (const float*)d_in[5];   // [3][2][52][26]
    const float* w_hhr = (const float*)d_in[6];   // [3][2][52][13]
    const float* b_ihr = (const float*)d_in[7];   // [3][2][52]
    const float* b_hhr = (const float*)d_in[8];   // [3][2][52]

    float* out = (float*)d_out;                   // [B][T][26]
    float* buf = (float*)d_ws;                    // [B][T][26] ping buffer

    dim3 grid(BATCH * 2), block(64);

    lstm_seq<13><<<grid, block, 0, stream>>>(x, w_ih0, w_hh0, b_ih0, b_hh0, buf);
    lstm_seq<26><<<grid, block, 0, stream>>>(
        buf, w_ihr + 0 * 2 * 52 * 26, w_hhr + 0 * 2 * 52 * 13,
        b_ihr + 0 * 2 * 52, b_hhr + 0 * 2 * 52, out);
    lstm_seq<26><<<grid, block, 0, stream>>>(
        out, w_ihr + 1 * 2 * 52 * 26, w_hhr + 1 * 2 * 52 * 13,
        b_ihr + 1 * 2 * 52, b_hhr + 1 * 2 * 52, buf);
    lstm_seq<26><<<grid, block, 0, stream>>>(
        buf, w_ihr + 2 * 2 * 52 * 26, w_hhr + 2 * 2 * 52 * 13,
        b_ihr + 2 * 2 * 52, b_hhr + 2 * 2 * 52, out);
}

// Round 7
// 2825.568 us; speedup vs baseline: 1.2691x; 1.2691x over previous
//
#include <hip/hip_runtime.h>

// 4-layer bidirectional LSTM, B=128, T=4096, H=13 (gates 4H=52).
// Producer/consumer: block = 2 waves per (batch, direction).
//   wave 1 (producer): computes gate pre-activations pre[s][lane] for the next
//     32-step chunk into double-buffered LDS (x-dot runs on its own SIMD).
//   wave 0 (consumer): pure recurrence -- per step: 13 readlane+FMA, one
//     exp2/rcp (gate act), DPP quad gather, cell FMA, exp2/rcp (tanh), store.
// Quad layout: lane l -> unit j=l>>2, gate q=l&3 (0=i,1=f,2=g,3=o).

constexpr int T_LEN = 4096;
constexpr int BATCH = 128;
constexpr int CH    = 32;                      // timesteps per pre chunk
constexpr float LOG2E = 1.4426950408889634f;

__device__ __forceinline__ float rl_f(float v, int lane) {
    return __int_as_float(__builtin_amdgcn_readlane(__float_as_int(v), lane));
}
template<int PAT>
__device__ __forceinline__ float qb(float v) {
    // quad_perm broadcast: 0x00->lane0, 0x55->lane1, 0xAA->lane2, 0xFF->lane3
    return __int_as_float(__builtin_amdgcn_update_dpp(0, __float_as_int(v), PAT, 0xf, 0xf, true));
}

template<int K>
__global__ __launch_bounds__(128, 1)
void lstm_pc(const float* __restrict__ act,   // [B][T][K]
             const float* __restrict__ wih,   // [2][52][K]
             const float* __restrict__ whh,   // [2][52][13]
             const float* __restrict__ bih,   // [2][52]
             const float* __restrict__ bhh,   // [2][52]
             float* __restrict__ out)         // [B][T][26]
{
    constexpr int RSF = (K == 13) ? 16 : 28;   // padded x-tile row floats
    constexpr int NCH = T_LEN / CH;

    const int tid  = threadIdx.x;
    const int lane = tid & 63;
    const int wid  = tid >> 6;                 // 0=consumer, 1=producer
    const int d    = blockIdx.x & 1;
    const int b    = blockIdx.x >> 1;
    const int q    = lane & 3;                 // gate: 0=i,1=f,2=g,3=o
    const int jj   = lane >> 2;
    const int j    = (jj < 13) ? jj : 12;
    const int r    = q * 13 + j;

    // pre-scales: pre-activation feeds exp2 directly; i-gate activation carries
    // -2log2e so the scaled cell state feeds exp2 with no serial mul.
    const float sq    = (q == 2) ? (-2.0f * LOG2E) : (-LOG2E);
    const float postA = (q == 0) ? (-2.0f * LOG2E) : ((q == 2) ? 2.0f : 1.0f);
    const float postB = (q == 2) ? -1.0f : 0.0f;

    __shared__ __align__(16) float pre[2][CH][64];   // 16 KiB
    __shared__ __align__(16) float xt[CH][RSF];      // x tile (producer-private)

    const float* actb = act + (size_t)b * T_LEN * K;

    // ---- producer state: input weights (pre-scaled) + bias ----
    float wi[K];
    float p0 = 0.0f;
    if (wid == 1) {
        const float* p = wih + (size_t)(d * 52 + r) * K;
        #pragma unroll
        for (int k = 0; k < K; ++k) wi[k] = p[k] * sq;
        p0 = (bih[d * 52 + r] + bhh[d * 52 + r]) * sq;
    }
    // ---- consumer state: recurrent weights (pre-scaled) ----
    float wh[13];
    if (wid == 0) {
        const float* p = whh + (size_t)(d * 52 + r) * 13;
        #pragma unroll
        for (int k = 0; k < 13; ++k) wh[k] = p[k] * sq;
    }

    // producer: stage chunk c's x rows into xt (bwd reversed), compute pre
    auto fill = [&](int c) {
        if (lane < CH) {
            const int gbase = d ? (T_LEN - CH * (c + 1)) : (CH * c);
            const float* p  = actb + (size_t)(gbase + lane) * K;
            float s0[K];
            if constexpr (K == 26) {
                const float2* p2 = reinterpret_cast<const float2*>(p);  // 8B aligned
                #pragma unroll
                for (int i = 0; i < 13; ++i) { float2 v = p2[i]; s0[2*i] = v.x; s0[2*i+1] = v.y; }
            } else {
                #pragma unroll
                for (int i = 0; i < K; ++i) s0[i] = p[i];
            }
            const int lrow = d ? (CH - 1 - lane) : lane;
            float* rowp = &xt[lrow][0];
            #pragma unroll
            for (int i = 0; i + 4 <= K; i += 4)
                *reinterpret_cast<float4*>(rowp + i) = make_float4(s0[i], s0[i+1], s0[i+2], s0[i+3]);
            if constexpr (K == 26)
                *reinterpret_cast<float2*>(rowp + 24) = make_float2(s0[24], s0[25]);
            else
                rowp[12] = s0[12];
        }
        // same-wave ds_write -> ds_read (compiler inserts lgkmcnt; no barrier needed)
        float* pb = &pre[c & 1][0][0];
        #pragma unroll 4
        for (int s = 0; s < CH; ++s) {
            const float* rowp = &xt[s][0];
            float c0 = p0, c1 = 0.f, c2 = 0.f, c3 = 0.f;
            #pragma unroll
            for (int i = 0; i + 4 <= K; i += 4) {
                float4 v = *reinterpret_cast<const float4*>(rowp + i);  // broadcast
                c0 = fmaf(v.x, wi[i],     c0);
                c1 = fmaf(v.y, wi[i + 1], c1);
                c2 = fmaf(v.z, wi[i + 2], c2);
                c3 = fmaf(v.w, wi[i + 3], c3);
            }
            if constexpr (K == 26) {
                float2 v = *reinterpret_cast<const float2*>(rowp + 24);
                c0 = fmaf(v.x, wi[24], c0);
                c1 = fmaf(v.y, wi[25], c1);
            } else {
                c0 = fmaf(rowp[12], wi[12], c0);
            }
            pb[s * 64 + lane] = (c0 + c1) + (c2 + c3);
        }
    };

    float hreg = 0.0f, cst = 0.0f;              // cst holds -2log2e * c
    float* outp = out + ((size_t)b * T_LEN + (d ? T_LEN - 1 : 0)) * 26 + d * 13 + j;
    const int ostep    = d ? -26 : 26;
    const bool dostore = (wid == 0) && (q == 0) && (jj < 13);

    if (wid == 1) fill(0);
    __syncthreads();

    for (int c = 0; c < NCH; ++c) {
        if (wid == 0) {
            // batch-read this chunk's 32 pre values (stride-1 lanes: conflict-free)
            float pv[CH];
            const float* pb = &pre[c & 1][0][0];
            #pragma unroll
            for (int s = 0; s < CH; ++s) pv[s] = pb[s * 64 + lane];
            #pragma unroll
            for (int s = 0; s < CH; ++s) {
                float b0 = pv[s], b1 = 0.f, b2 = 0.f, b3 = 0.f;
                #pragma unroll
                for (int k = 0; k < 13; ++k) {
                    float hk = rl_f(hreg, 4 * k);      // const-lane readlane
                    if ((k & 3) == 0) b0 = fmaf(hk, wh[k], b0);
                    else if ((k & 3) == 1) b1 = fmaf(hk, wh[k], b1);
                    else if ((k & 3) == 2) b2 = fmaf(hk, wh[k], b2);
                    else b3 = fmaf(hk, wh[k], b3);
                }
                float acc = (b0 + b1) + (b2 + b3);
                float u   = __builtin_amdgcn_exp2f(acc);
                float sg  = __builtin_amdgcn_rcpf(1.0f + u);
                float a   = fmaf(postA, sg, postB);    // sigmoid / tanh / -2log2e*sig(i)
                float iv = qb<0x00>(a);
                float fv = qb<0x55>(a);
                float gv = qb<0xAA>(a);
                float ov = qb<0xFF>(a);
                float ivg = iv * gv;                   // carries -2log2e
                cst = fmaf(fv, cst, ivg);              // scaled cell state
                float u2  = __builtin_amdgcn_exp2f(cst);
                float r2  = __builtin_amdgcn_rcpf(1.0f + u2);
                float ov2 = ov + ov;
                hreg = fmaf(ov2, r2, -ov);             // ov*tanh(c)
                if (dostore) *outp = hreg;
                outp += ostep;
            }
        } else if (c + 1 < NCH) {
            fill(c + 1);
        }
        __syncthreads();
    }
}

extern "C" void kernel_launch(void* const* d_in, const int* in_sizes, int n_in,
                              void* d_out, int out_size, void* d_ws, size_t ws_size,
                              hipStream_t stream) {
    const float* x     = (const float*)d_in[0];
    const float* w_ih0 = (const float*)d_in[1];
    const float* w_hh0 = (const float*)d_in[2];
    const float* b_ih0 = (const float*)d_in[3];
    const float* b_hh0 = (const float*)d_in[4];
    const float* w_ihr = (const float*)d_in[5];   // [3][2][52][26]
    const float* w_hhr = (const float*)d_in[6];   // [3][2][52][13]
    const float* b_ihr = (const float*)d_in[7];   // [3][2][52]
    const float* b_hhr = (const float*)d_in[8];   // [3][2][52]

    float* out = (float*)d_out;                   // [B][T][26]
    float* buf = (float*)d_ws;                    // [B][T][26] ping buffer

    dim3 grid(BATCH * 2), block(128);

    lstm_pc<13><<<grid, block, 0, stream>>>(x, w_ih0, w_hh0, b_ih0, b_hh0, buf);
    lstm_pc<26><<<grid, block, 0, stream>>>(
        buf, w_ihr + 0 * 2 * 52 * 26, w_hhr + 0 * 2 * 52 * 13,
        b_ihr + 0 * 2 * 52, b_hhr + 0 * 2 * 52, out);
    lstm_pc<26><<<grid, block, 0, stream>>>(
        out, w_ihr + 1 * 2 * 52 * 26, w_hhr + 1 * 2 * 52 * 13,
        b_ihr + 1 * 2 * 52, b_hhr + 1 * 2 * 52, buf);
    lstm_pc<26><<<grid, block, 0, stream>>>(
        buf, w_ihr + 2 * 2 * 52 * 26, w_hhr + 2 * 2 * 52 * 13,
        b_ihr + 2 * 2 * 52, b_hhr + 2 * 2 * 52, out);
}

// Round 9
// 2690.129 us; speedup vs baseline: 1.3330x; 1.0503x over previous
//
#include <hip/hip_runtime.h>

// 4-layer bidirectional LSTM, B=128, T=4096, H=13 (gates 4H=52).
// Producer/consumer, block = 2 waves per (batch, direction).
//   wave 0 (consumer): bare recurrence only. Per step: 13 readlane+FMA,
//     exp2/rcp (gate act), 4 DPP quad gather, cell FMA, exp2/rcp (tanh),
//     one unmasked ds_write_b32 of h to LDS. No global stores, no pointer math.
//   wave 1 (producer): computes pre-activations for chunk c+1, drains chunk
//     c-1's h values from LDS to global, and register-prefetches x for chunk
//     c+2 (so its fill window is deterministic LDS+FMA, never HBM-bound).
// Quad layout: lane l -> unit j=l>>2, gate q=l&3 (0=i,1=f,2=g,3=o).

constexpr int T_LEN = 4096;
constexpr int BATCH = 128;
constexpr int CH    = 32;                      // timesteps per chunk
constexpr int NCH   = T_LEN / CH;
constexpr float LOG2E = 1.4426950408889634f;

__device__ __forceinline__ float rl_f(float v, int lane) {
    return __int_as_float(__builtin_amdgcn_readlane(__float_as_int(v), lane));
}
template<int PAT>
__device__ __forceinline__ float qb(float v) {
    // quad_perm broadcast: 0x00->lane0, 0x55->lane1, 0xAA->lane2, 0xFF->lane3
    return __int_as_float(__builtin_amdgcn_update_dpp(0, __float_as_int(v), PAT, 0xf, 0xf, true));
}

template<int K>
__global__ __launch_bounds__(128, 1)
void lstm_pc(const float* __restrict__ act,   // [B][T][K]
             const float* __restrict__ wih,   // [2][52][K]
             const float* __restrict__ whh,   // [2][52][13]
             const float* __restrict__ bih,   // [2][52]
             const float* __restrict__ bhh,   // [2][52]
             float* __restrict__ out)         // [B][T][26]
{
    constexpr int RSF = (K == 13) ? 16 : 28;   // padded x-tile row floats

    const int tid  = threadIdx.x;
    const int lane = tid & 63;
    const int wid  = tid >> 6;                 // 0=consumer, 1=producer
    const int d    = blockIdx.x & 1;
    const int b    = blockIdx.x >> 1;
    const int q    = lane & 3;                 // gate: 0=i,1=f,2=g,3=o
    const int jj   = lane >> 2;
    const int j    = (jj < 13) ? jj : 12;
    const int r    = q * 13 + j;

    // pre-scales: pre-activation feeds exp2 directly; i-gate activation carries
    // -2log2e so the scaled cell state feeds exp2 with no serial mul.
    const float sq    = (q == 2) ? (-2.0f * LOG2E) : (-LOG2E);
    const float postA = (q == 0) ? (-2.0f * LOG2E) : ((q == 2) ? 2.0f : 1.0f);
    const float postB = (q == 2) ? -1.0f : 0.0f;

    __shared__ __align__(16) float pre[2][CH][64];   // 16 KiB (gate pre-acts)
    __shared__ __align__(16) float hs[2][CH][64];    // 16 KiB (h handoff)
    __shared__ __align__(16) float xt[CH][RSF];      // x tile (producer-private)

    const float* actb = act + (size_t)b * T_LEN * K;

    // ---- producer state ----
    float wi[K];
    float p0 = 0.0f;
    float xr[K];                               // register-prefetched x row
    // ---- consumer state ----
    float wh[13];

    if (wid == 1) {
        const float* p = wih + (size_t)(d * 52 + r) * K;
        #pragma unroll
        for (int k = 0; k < K; ++k) wi[k] = p[k] * sq;
        p0 = (bih[d * 52 + r] + bhh[d * 52 + r]) * sq;
    } else {
        const float* p = whh + (size_t)(d * 52 + r) * 13;
        #pragma unroll
        for (int k = 0; k < 13; ++k) wh[k] = p[k] * sq;
    }

    // producer: global-load chunk c's x rows into registers (lane < CH only)
    auto loadx = [&](int c) {
        if (lane < CH) {
            const int gbase = d ? (T_LEN - CH * (c + 1)) : (CH * c);
            const float* p  = actb + (size_t)(gbase + lane) * K;
            if constexpr (K == 26) {
                const float2* p2 = reinterpret_cast<const float2*>(p);  // 8B aligned
                #pragma unroll
                for (int i = 0; i < 13; ++i) { float2 v = p2[i]; xr[2*i] = v.x; xr[2*i+1] = v.y; }
            } else {
                #pragma unroll
                for (int i = 0; i < K; ++i) xr[i] = p[i];
            }
        }
    };
    // producer: xr (one chunk's rows) -> xt (bwd reversed), then compute pre[cp&1]
    auto fill_from_regs = [&](int cp) {
        if (lane < CH) {
            const int lrow = d ? (CH - 1 - lane) : lane;
            float* rowp = &xt[lrow][0];
            #pragma unroll
            for (int i = 0; i + 4 <= K; i += 4)
                *reinterpret_cast<float4*>(rowp + i) = make_float4(xr[i], xr[i+1], xr[i+2], xr[i+3]);
            if constexpr (K == 26)
                *reinterpret_cast<float2*>(rowp + 24) = make_float2(xr[24], xr[25]);
            else
                rowp[12] = xr[12];
        }
        // same-wave ds_write -> ds_read: lgkmcnt ordering, no barrier needed
        float* pb = &pre[cp & 1][0][0];
        #pragma unroll 4
        for (int s = 0; s < CH; ++s) {
            const float* rowp = &xt[s][0];
            float c0 = p0, c1 = 0.f, c2 = 0.f, c3 = 0.f;
            #pragma unroll
            for (int i = 0; i + 4 <= K; i += 4) {
                float4 v = *reinterpret_cast<const float4*>(rowp + i);  // broadcast
                c0 = fmaf(v.x, wi[i],     c0);
                c1 = fmaf(v.y, wi[i + 1], c1);
                c2 = fmaf(v.z, wi[i + 2], c2);
                c3 = fmaf(v.w, wi[i + 3], c3);
            }
            if constexpr (K == 26) {
                float2 v = *reinterpret_cast<const float2*>(rowp + 24);
                c0 = fmaf(v.x, wi[24], c0);
                c1 = fmaf(v.y, wi[25], c1);
            } else {
                c0 = fmaf(rowp[12], wi[12], c0);
            }
            pb[s * 64 + lane] = (c0 + c1) + (c2 + c3);
        }
    };
    // producer: drain chunk cc's h values (LDS -> global)
    auto store_hs = [&](int cc) {
        if (lane < 13) {
            const int tb = d ? (T_LEN - 1 - CH * cc) : (CH * cc);
            const float* hb = &hs[cc & 1][0][0];
            float* op = out + ((size_t)b * T_LEN + tb) * 26 + d * 13 + lane;
            const ptrdiff_t os = d ? -26 : 26;
            #pragma unroll 8
            for (int s = 0; s < CH; ++s) { *op = hb[s * 64 + 4 * lane]; op += os; }
        }
    };

    if (wid == 1) {
        loadx(0);
        fill_from_regs(0);                      // pre for chunk 0
        loadx(1);                               // chunk 1 x -> regs
    }
    __syncthreads();

    float hreg = 0.0f, cst = 0.0f;              // cst holds -2log2e * c

    for (int c = 0; c < NCH; ++c) {
        if (wid == 0) {
            const float* pb = &pre[c & 1][0][0];
            float* hb = &hs[c & 1][0][0];
            float pv[CH];
            #pragma unroll
            for (int s = 0; s < CH; ++s) pv[s] = pb[s * 64 + lane];  // stride-1: free
            #pragma unroll
            for (int s = 0; s < CH; ++s) {
                float b0 = pv[s], b1 = 0.f, b2 = 0.f, b3 = 0.f;
                #pragma unroll
                for (int k = 0; k < 13; ++k) {
                    float hk = rl_f(hreg, 4 * k);      // const-lane readlane
                    if ((k & 3) == 0) b0 = fmaf(hk, wh[k], b0);
                    else if ((k & 3) == 1) b1 = fmaf(hk, wh[k], b1);
                    else if ((k & 3) == 2) b2 = fmaf(hk, wh[k], b2);
                    else b3 = fmaf(hk, wh[k], b3);
                }
                float acc = (b0 + b1) + (b2 + b3);
                float u   = __builtin_amdgcn_exp2f(acc);
                float sg  = __builtin_amdgcn_rcpf(1.0f + u);
                float a   = fmaf(postA, sg, postB);    // sigmoid / tanh / -2log2e*sig(i)
                float iv = qb<0x00>(a);
                float fv = qb<0x55>(a);
                float gv = qb<0xAA>(a);
                float ov = qb<0xFF>(a);
                float ivg = iv * gv;                   // carries -2log2e
                cst = fmaf(fv, cst, ivg);              // scaled cell state
                float u2  = __builtin_amdgcn_exp2f(cst);
                float r2  = __builtin_amdgcn_rcpf(1.0f + u2);
                float ov2 = ov + ov;
                hreg = fmaf(ov2, r2, -ov);             // ov*tanh(c)
                hb[s * 64 + lane] = hreg;              // unmasked, stride-1, no wait
            }
        } else {
            if (c > 0) store_hs(c - 1);                // drain previous chunk's h
            if (c + 1 < NCH) fill_from_regs(c + 1);    // pre for next chunk (regs only)
            if (c + 2 < NCH) loadx(c + 2);             // issue HBM loads 2 chunks ahead
        }
        __syncthreads();
    }
    if (wid == 1) store_hs(NCH - 1);                   // final drain
}

extern "C" void kernel_launch(void* const* d_in, const int* in_sizes, int n_in,
                              void* d_out, int out_size, void* d_ws, size_t ws_size,
                              hipStream_t stream) {
    const float* x     = (const float*)d_in[0];
    const float* w_ih0 = (const float*)d_in[1];
    const float* w_hh0 = (const float*)d_in[2];
    const float* b_ih0 = (const float*)d_in[3];
    const float* b_hh0 = (const float*)d_in[4];
    const float* w_ihr = (const float*)d_in[5];   // [3][2][52][26]
    const float* w_hhr = (const float*)d_in[6];   // [3][2][52][13]
    const float* b_ihr = (const float*)d_in[7];   // [3][2][52]
    const float* b_hhr = (const float*)d_in[8];   // [3][2][52]

    float* out = (float*)d_out;                   // [B][T][26]
    float* buf = (float*)d_ws;                    // [B][T][26] ping buffer

    dim3 grid(BATCH * 2), block(128);

    lstm_pc<13><<<grid, block, 0, stream>>>(x, w_ih0, w_hh0, b_ih0, b_hh0, buf);
    lstm_pc<26><<<grid, block, 0, stream>>>(
        buf, w_ihr + 0 * 2 * 52 * 26, w_hhr + 0 * 2 * 52 * 13,
        b_ihr + 0 * 2 * 52, b_hhr + 0 * 2 * 52, out);
    lstm_pc<26><<<grid, block, 0, stream>>>(
        out, w_ihr + 1 * 2 * 52 * 26, w_hhr + 1 * 2 * 52 * 13,
        b_ihr + 1 * 2 * 52, b_hhr + 1 * 2 * 52, buf);
    lstm_pc<26><<<grid, block, 0, stream>>>(
        buf, w_ihr + 2 * 2 * 52 * 26, w_hhr + 2 * 2 * 52 * 13,
        b_ihr + 2 * 2 * 52, b_hhr + 2 * 2 * 52, out);
}

// Round 11
// 1647.005 us; speedup vs baseline: 2.1773x; 1.6333x over previous
//
#include <hip/hip_runtime.h>

// 4-layer bidirectional LSTM, B=128, T=4096, H=13 (gates 4H=52).
// 3 waves per (batch, direction):
//   wave 0 (consumer): bare recurrence (unchanged from R7). Per step: 13
//     readlane+FMA, exp2/rcp, 4 DPP gather, cell FMA, exp2/rcp, ds_write h.
//   waves 1,2 (producers): each owns 16 of the 32 chunk timesteps — loads its
//     16 x rows, computes its 16 pre rows, drains its 16 h values (batched
//     LDS reads -> regs -> global stores), prefetches x 2 chunks ahead.
// Quad layout: lane l -> unit j=l>>2, gate q=l&3 (0=i,1=f,2=g,3=o).

constexpr int T_LEN = 4096;
constexpr int BATCH = 128;
constexpr int CH    = 32;                      // timesteps per chunk
constexpr int HCH   = 16;                      // per-producer half chunk
constexpr int NCH   = T_LEN / CH;
constexpr float LOG2E = 1.4426950408889634f;

__device__ __forceinline__ float rl_f(float v, int lane) {
    return __int_as_float(__builtin_amdgcn_readlane(__float_as_int(v), lane));
}
template<int PAT>
__device__ __forceinline__ float qb(float v) {
    // quad_perm broadcast: 0x00->lane0, 0x55->lane1, 0xAA->lane2, 0xFF->lane3
    return __int_as_float(__builtin_amdgcn_update_dpp(0, __float_as_int(v), PAT, 0xf, 0xf, true));
}

template<int K>
__global__ __launch_bounds__(192, 1)
void lstm_pc(const float* __restrict__ act,   // [B][T][K]
             const float* __restrict__ wih,   // [2][52][K]
             const float* __restrict__ whh,   // [2][52][13]
             const float* __restrict__ bih,   // [2][52]
             const float* __restrict__ bhh,   // [2][52]
             float* __restrict__ out)         // [B][T][26]
{
    constexpr int RSF = (K == 13) ? 16 : 28;   // padded x-tile row floats

    const int tid  = threadIdx.x;
    const int lane = tid & 63;
    const int wid  = tid >> 6;                 // 0=consumer, 1/2=producers
    const int base = (wid - 1) * HCH;          // producer half offset (garbage for wid0)
    const int d    = blockIdx.x & 1;
    const int b    = blockIdx.x >> 1;
    const int q    = lane & 3;                 // gate: 0=i,1=f,2=g,3=o
    const int jj   = lane >> 2;
    const int j    = (jj < 13) ? jj : 12;
    const int r    = q * 13 + j;

    // pre-scales: pre-activation feeds exp2 directly; i-gate activation carries
    // -2log2e so the scaled cell state feeds exp2 with no serial mul.
    const float sq    = (q == 2) ? (-2.0f * LOG2E) : (-LOG2E);
    const float postA = (q == 0) ? (-2.0f * LOG2E) : ((q == 2) ? 2.0f : 1.0f);
    const float postB = (q == 2) ? -1.0f : 0.0f;

    __shared__ __align__(16) float pre[2][CH][64];   // 16 KiB (gate pre-acts)
    __shared__ __align__(16) float hs[2][CH][64];    // 16 KiB (h handoff)
    __shared__ __align__(16) float xt[CH][RSF];      // x tile (per-producer halves)

    const float* actb = act + (size_t)b * T_LEN * K;

    // ---- producer state ----
    float wi[K];
    float p0 = 0.0f;
    float xr[K];                               // register-prefetched x row
    // ---- consumer state ----
    float wh[13];

    if (wid != 0) {
        const float* p = wih + (size_t)(d * 52 + r) * K;
        #pragma unroll
        for (int k = 0; k < K; ++k) wi[k] = p[k] * sq;
        p0 = (bih[d * 52 + r] + bhh[d * 52 + r]) * sq;
    } else {
        const float* p = whh + (size_t)(d * 52 + r) * 13;
        #pragma unroll
        for (int k = 0; k < 13; ++k) wh[k] = p[k] * sq;
    }

    // producer: load the global x row that maps to LDS time-row (base+lane)
    auto loadx = [&](int c) {
        if (lane < HCH) {
            const int lrow  = base + lane;                       // time order in chunk
            const int gbase = d ? (T_LEN - CH * (c + 1)) : (CH * c);
            const int grow  = d ? (CH - 1 - lrow) : lrow;        // bwd: reversed
            const float* p  = actb + (size_t)(gbase + grow) * K;
            if constexpr (K == 26) {
                const float2* p2 = reinterpret_cast<const float2*>(p);  // 8B aligned
                #pragma unroll
                for (int i = 0; i < 13; ++i) { float2 v = p2[i]; xr[2*i] = v.x; xr[2*i+1] = v.y; }
            } else {
                #pragma unroll
                for (int i = 0; i < K; ++i) xr[i] = p[i];
            }
        }
    };
    // producer: xr -> xt (own half), then compute own 16 pre rows
    auto fill_from_regs = [&](int cp) {
        if (lane < HCH) {
            float* rowp = &xt[base + lane][0];
            #pragma unroll
            for (int i = 0; i + 4 <= K; i += 4)
                *reinterpret_cast<float4*>(rowp + i) = make_float4(xr[i], xr[i+1], xr[i+2], xr[i+3]);
            if constexpr (K == 26)
                *reinterpret_cast<float2*>(rowp + 24) = make_float2(xr[24], xr[25]);
            else
                rowp[12] = xr[12];
        }
        // same-wave ds_write -> ds_read: lgkmcnt ordering, no barrier needed
        float* pb = &pre[cp & 1][0][0];
        #pragma unroll 4
        for (int s = 0; s < HCH; ++s) {
            const float* rowp = &xt[base + s][0];
            float c0 = p0, c1 = 0.f, c2 = 0.f, c3 = 0.f;
            #pragma unroll
            for (int i = 0; i + 4 <= K; i += 4) {
                float4 v = *reinterpret_cast<const float4*>(rowp + i);  // broadcast
                c0 = fmaf(v.x, wi[i],     c0);
                c1 = fmaf(v.y, wi[i + 1], c1);
                c2 = fmaf(v.z, wi[i + 2], c2);
                c3 = fmaf(v.w, wi[i + 3], c3);
            }
            if constexpr (K == 26) {
                float2 v = *reinterpret_cast<const float2*>(rowp + 24);
                c0 = fmaf(v.x, wi[24], c0);
                c1 = fmaf(v.y, wi[25], c1);
            } else {
                c0 = fmaf(rowp[12], wi[12], c0);
            }
            pb[(base + s) * 64 + lane] = (c0 + c1) + (c2 + c3);
        }
    };
    // producer: drain own 16 h values of chunk cc (batch reads, then stores)
    auto store_hs = [&](int cc) {
        if (lane < 13) {
            const float* hb = &hs[cc & 1][0][0];
            float hv[HCH];
            #pragma unroll
            for (int s = 0; s < HCH; ++s) hv[s] = hb[(base + s) * 64 + 4 * lane];
            const int t0 = cc * CH + base;                       // time order
            const int tt0 = d ? (T_LEN - 1 - t0) : t0;
            float* op = out + ((size_t)b * T_LEN + tt0) * 26 + d * 13 + lane;
            const ptrdiff_t os = d ? -26 : 26;
            #pragma unroll
            for (int s = 0; s < HCH; ++s) { *op = hv[s]; op += os; }
        }
    };

    if (wid != 0) {
        loadx(0);
        fill_from_regs(0);                      // pre for chunk 0 (own half)
        loadx(1);                               // chunk 1 x -> regs
    }
    __syncthreads();

    float hreg = 0.0f, cst = 0.0f;              // cst holds -2log2e * c

    for (int c = 0; c < NCH; ++c) {
        if (wid == 0) {
            const float* pb = &pre[c & 1][0][0];
            float* hb = &hs[c & 1][0][0];
            float pv[CH];
            #pragma unroll
            for (int s = 0; s < CH; ++s) pv[s] = pb[s * 64 + lane];  // stride-1: free
            #pragma unroll
            for (int s = 0; s < CH; ++s) {
                float b0 = pv[s], b1 = 0.f, b2 = 0.f, b3 = 0.f;
                #pragma unroll
                for (int k = 0; k < 13; ++k) {
                    float hk = rl_f(hreg, 4 * k);      // const-lane readlane
                    if ((k & 3) == 0) b0 = fmaf(hk, wh[k], b0);
                    else if ((k & 3) == 1) b1 = fmaf(hk, wh[k], b1);
                    else if ((k & 3) == 2) b2 = fmaf(hk, wh[k], b2);
                    else b3 = fmaf(hk, wh[k], b3);
                }
                float acc = (b0 + b1) + (b2 + b3);
                float u   = __builtin_amdgcn_exp2f(acc);
                float sg  = __builtin_amdgcn_rcpf(1.0f + u);
                float a   = fmaf(postA, sg, postB);    // sigmoid / tanh / -2log2e*sig(i)
                float iv = qb<0x00>(a);
                float fv = qb<0x55>(a);
                float gv = qb<0xAA>(a);
                float ov = qb<0xFF>(a);
                float ivg = iv * gv;                   // carries -2log2e
                cst = fmaf(fv, cst, ivg);              // scaled cell state
                float u2  = __builtin_amdgcn_exp2f(cst);
                float r2  = __builtin_amdgcn_rcpf(1.0f + u2);
                float ov2 = ov + ov;
                hreg = fmaf(ov2, r2, -ov);             // ov*tanh(c)
                hb[s * 64 + lane] = hreg;              // unmasked, stride-1, no wait
            }
        } else {
            if (c > 0) store_hs(c - 1);                // drain previous chunk (own half)
            if (c + 1 < NCH) fill_from_regs(c + 1);    // pre for next chunk (regs only)
            if (c + 2 < NCH) loadx(c + 2);             // issue HBM loads 2 chunks ahead
        }
        __syncthreads();
    }
    if (wid != 0) store_hs(NCH - 1);                   // final drain
}

extern "C" void kernel_launch(void* const* d_in, const int* in_sizes, int n_in,
                              void* d_out, int out_size, void* d_ws, size_t ws_size,
                              hipStream_t stream) {
    const float* x     = (const float*)d_in[0];
    const float* w_ih0 = (const float*)d_in[1];
    const float* w_hh0 = (const float*)d_in[2];
    const float* b_ih0 = (const float*)d_in[3];
    const float* b_hh0 = (const float*)d_in[4];
    const float* w_ihr = (const float*)d_in[5];   // [3][2][52][26]
    const float* w_hhr = (const float*)d_in[6];   // [3][2][52][13]
    const float* b_ihr = (const float*)d_in[7];   // [3][2][52]
    const float* b_hhr = (const float*)d_in[8];   // [3][2][52]

    float* out = (float*)d_out;                   // [B][T][26]
    float* buf = (float*)d_ws;                    // [B][T][26] ping buffer

    dim3 grid(BATCH * 2), block(192);

    lstm_pc<13><<<grid, block, 0, stream>>>(x, w_ih0, w_hh0, b_ih0, b_hh0, buf);
    lstm_pc<26><<<grid, block, 0, stream>>>(
        buf, w_ihr + 0 * 2 * 52 * 26, w_hhr + 0 * 2 * 52 * 13,
        b_ihr + 0 * 2 * 52, b_hhr + 0 * 2 * 52, out);
    lstm_pc<26><<<grid, block, 0, stream>>>(
        out, w_ihr + 1 * 2 * 52 * 26, w_hhr + 1 * 2 * 52 * 13,
        b_ihr + 1 * 2 * 52, b_hhr + 1 * 2 * 52, buf);
    lstm_pc<26><<<grid, block, 0, stream>>>(
        buf, w_ihr + 2 * 2 * 52 * 26, w_hhr + 2 * 2 * 52 * 13,
        b_ihr + 2 * 2 * 52, b_hhr + 2 * 2 * 52, out);
}